// Round 7
// baseline (776.736 us; speedup 1.0000x reference)
//
#include <hip/hip_runtime.h>
#include <hip/hip_fp16.h>

#define N_NODES 50000
#define N_EDGES 800000
#define N_GRAPHS 64
#define N_PAD 50048

#define CB 256                              // coarse-pass blocks
#define EPB (N_EDGES / CB)                  // 3125 edges per block (exact)
#define NBUCKET ((N_NODES + 255) / 256)     // 196 coarse buckets (dst>>8)

typedef _Float16 f16x8 __attribute__((ext_vector_type(8)));
typedef float f32x4 __attribute__((ext_vector_type(4)));

// ---------------- prep: Wt2->fp16, Wcb = ([W_in;b_in]@W1)^T fp16 (K pad 8), zeros ----

__global__ void k_prep(const float* __restrict__ W_in, const float* __restrict__ b_in,
                       const float* __restrict__ W1, const float* __restrict__ W2,
                       _Float16* __restrict__ Wt2, _Float16* __restrict__ Wcb,
                       float* psum, float* pmax, int* totals) {
    int idx = blockIdx.x * blockDim.x + threadIdx.x;
    if (idx < 128 * 128) {                   // Wt2[n*128+k] = W2[k*128+n]
        int n = idx >> 7, k = idx & 127;
        Wt2[idx] = (_Float16)W2[k * 128 + n];
    } else if (idx < 128 * 128 + 1024) {     // Wcb[n*8+k] = Wc[k][n], row 7 = 0
        int j = idx - 128 * 128;
        int n = j >> 3, k = j & 7;
        float acc = 0.f;
        if (k < 6) {
            for (int q = 0; q < 64; q++) acc += W_in[k * 64 + q] * W1[q * 128 + n];
        } else if (k == 6) {
            for (int q = 0; q < 64; q++) acc += b_in[q] * W1[q * 128 + n];
        }
        Wcb[j] = (_Float16)acc;              // k==7 stays 0
    }
    if (idx < N_GRAPHS * 128) { psum[idx] = 0.f; pmax[idx] = 0.f; }
    if (idx < 256) totals[idx] = 0;
}

// ---------------- CSR build (round-0 proven form) ----------------

__global__ __launch_bounds__(256) void k_coarse_hist(const int* __restrict__ dst,
                                                     int* __restrict__ totals) {
    __shared__ int hist[NBUCKET];
    int t = threadIdx.x, b = blockIdx.x;
    for (int i = t; i < NBUCKET; i += 256) hist[i] = 0;
    __syncthreads();
    int e0 = b * EPB;
    for (int e = e0 + t; e < e0 + EPB; e += 256)
        atomicAdd(&hist[dst[e] >> 8], 1);
    __syncthreads();
    for (int i = t; i < NBUCKET; i += 256)
        if (hist[i] > 0) atomicAdd(&totals[i], hist[i]);
}

__global__ void k_bucket_scan(const int* __restrict__ totals, int* __restrict__ bucket_base,
                              int* __restrict__ gcursor, const int* __restrict__ batch,
                              float* __restrict__ pcnt) {
    __shared__ int sh[256];
    int t = threadIdx.x;
    int v = (t < NBUCKET) ? totals[t] : 0;
    sh[t] = v;
    __syncthreads();
    for (int off = 1; off < 256; off <<= 1) {
        int u = (t >= off) ? sh[t - off] : 0;
        __syncthreads();
        sh[t] += u;
        __syncthreads();
    }
    if (t < NBUCKET) {
        int base = sh[t] - v;
        bucket_base[t] = base;
        gcursor[t] = base;
    }
    if (t == 0) bucket_base[NBUCKET] = N_EDGES;
    if (t <= N_GRAPHS) {
        int lo = 0, hi = N_NODES;
        while (lo < hi) {
            int mid = (lo + hi) >> 1;
            if (batch[mid] < t) lo = mid + 1; else hi = mid;
        }
        sh[t] = lo;
    }
    __syncthreads();
    if (t < N_GRAPHS) pcnt[t] = (float)(sh[t + 1] - sh[t]);
}

__global__ __launch_bounds__(256) void k_coarse_scatter(
        const int* __restrict__ src, const int* __restrict__ dst,
        int* __restrict__ gcursor, unsigned int* __restrict__ esort) {
    __shared__ int cur[NBUCKET];
    int t = threadIdx.x, b = blockIdx.x;
    for (int i = t; i < NBUCKET; i += 256) cur[i] = 0;
    __syncthreads();
    int e0 = b * EPB;
    for (int e = e0 + t; e < e0 + EPB; e += 256)
        atomicAdd(&cur[dst[e] >> 8], 1);
    __syncthreads();
    for (int i = t; i < NBUCKET; i += 256) {
        int cnt = cur[i];
        cur[i] = (cnt > 0) ? atomicAdd(&gcursor[i], cnt) : 0;
    }
    __syncthreads();
    for (int e = e0 + t; e < e0 + EPB; e += 256) {
        int d = dst[e];
        int slot = atomicAdd(&cur[d >> 8], 1);
        esort[slot] = ((unsigned)(d & 255) << 16) | (unsigned)src[e];  // src < 2^16
    }
}

// fine hist -> row_ptr/dinv, cursor fill of col; store p[node] = dinv*[x0..x5, 1, 0]
__global__ __launch_bounds__(256) void k_fine_fill_p(
        const unsigned int* __restrict__ esort, const int* __restrict__ bucket_base,
        int* __restrict__ col, int* __restrict__ row_ptr, float* __restrict__ dinv,
        const float* __restrict__ x, float* __restrict__ p) {
    __shared__ int hist[256];
    __shared__ int sc[256];
    __shared__ int cur[256];
    int t = threadIdx.x, b = blockIdx.x;
    hist[t] = 0;
    __syncthreads();
    int base = bucket_base[b], end = bucket_base[b + 1];
    for (int e = base + t; e < end; e += 256)
        atomicAdd(&hist[(esort[e] >> 16) & 255], 1);
    __syncthreads();
    int v = hist[t];
    sc[t] = v;
    __syncthreads();
    for (int off = 1; off < 256; off <<= 1) {
        int u = (t >= off) ? sc[t - off] : 0;
        __syncthreads();
        sc[t] += u;
        __syncthreads();
    }
    int start = base + sc[t] - v;
    cur[t] = start;
    int node = b * 256 + t;
    float di = rsqrtf((float)(v + 1));  // +1 self-loop
    if (node < N_NODES) {
        row_ptr[node] = start;
        dinv[node] = di;
        float pr[8];
#pragma unroll
        for (int k = 0; k < 6; k++) pr[k] = x[node * 6 + k] * di;
        pr[6] = di;      // multiplies the fused bias row (b_in@W1)
        pr[7] = 0.f;
        *(f32x4*)&p[(size_t)node * 8] = *(f32x4*)&pr[0];
        *(f32x4*)&p[(size_t)node * 8 + 4] = *(f32x4*)&pr[4];
    }
    if (b == 0 && t == 0) row_ptr[N_NODES] = N_EDGES;
    __syncthreads();
    for (int e = base + t; e < end; e += 256) {
        unsigned pk = esort[e];
        int slot = atomicAdd(&cur[(pk >> 16) & 255], 1);
        col[slot] = (int)(pk & 0xffffu);
    }
}

// ---------------- layer 1 state: t16s[i] = fp16( di_i * [t_i(0..6), 1] ) -------------
// Gather phase identical to the proven k_agg_proj (1 transaction/edge, pfeat fp32,
// L2-resident 1.6 MB); projection REMOVED — we only store the 16B pre-proj state.
__global__ __launch_bounds__(256, 8) void k_agg_t(
        const float* __restrict__ p, const int* __restrict__ row_ptr,
        const int* __restrict__ col, const float* __restrict__ dinv,
        _Float16* __restrict__ t16s, int n) {
    int t = threadIdx.x;
    int rg = t >> 3, ck = t & 7;
    int row = blockIdx.x * 32 + rg;
    float acc = 0.f;
    if (row < n) {
        acc = p[(size_t)row * 8 + ck];  // self term
        int e = row_ptr[row], e1 = row_ptr[row + 1];
        for (; e + 3 < e1; e += 4) {
            int c0 = col[e], c1 = col[e + 1], c2 = col[e + 2], c3 = col[e + 3];
            float v0 = p[(size_t)c0 * 8 + ck];
            float v1 = p[(size_t)c1 * 8 + ck];
            float v2 = p[(size_t)c2 * 8 + ck];
            float v3 = p[(size_t)c3 * 8 + ck];
            acc += (v0 + v1) + (v2 + v3);
        }
        for (; e < e1; e++) acc += p[(size_t)col[e] * 8 + ck];
        float di = dinv[row];
        float val = (ck == 7) ? di : acc * di;   // slot7 carries di for post-relu scale
        t16s[(size_t)row * 8 + ck] = (_Float16)val;
    }
}

// ---------------- layer 2: edge-recompute + LDS aggregate + W2 MFMA + pooling --------
// Per edge: ONE 16B request (t16s[src]); g1[src] recomputed on the fly:
//   z = (di*t)@Wc  (MFMA, K=8 real padded to 32: quads 1-3 carry zero frags)
//   g1 = relu(z + b1) * di_src   -> LDS atomicAdd into agg[dst_local][ch] (fp32)
// Then h2 = relu(di_dst*(agg@W2)+b2) + fused pooling (proven round-0 epilogue).
#define MAXE 448
__global__ __launch_bounds__(256, 4) void k_gnn2r(
        const _Float16* __restrict__ t16s, const int* __restrict__ row_ptr,
        const int* __restrict__ col, const _Float16* __restrict__ Wcb,
        const float* __restrict__ b1v, const _Float16* __restrict__ Wt2,
        const float* __restrict__ b2v, const float* __restrict__ dinv,
        const int* __restrict__ batch, float* __restrict__ psum,
        float* __restrict__ pmax, int n) {
    constexpr int ROWS = 16;
    constexpr int ASTR = 132;                  // accum stride (pad: avoid 16-way banks)
    __shared__ __align__(16) _Float16 estage[MAXE * 8];   // 7 KB  [edge][8]
    __shared__ unsigned short edst[MAXE];                 // 0.9 KB
    __shared__ float accum[ROWS * ASTR];                  // 8.25 KB
    __shared__ int rowb[ROWS + 1];
    __shared__ float Hs[ROWS * 128];                      // 8 KB
    __shared__ __align__(16) _Float16 WcbL[128 * 8];      // 2 KB
    int t = threadIdx.x;
    int r0 = blockIdx.x * ROWS;

    for (int i = t; i < 128 * 8; i += 256) WcbL[i] = Wcb[i];
    if (t <= ROWS) rowb[t] = row_ptr[r0 + t];
    for (int i = t; i < ROWS * ASTR; i += 256) accum[i] = 0.f;
    __syncthreads();
    int e0 = rowb[0];
    int ecount = rowb[ROWS] - e0;
    int etot = ecount + ROWS;                  // + 16 self edges (slots 0..15)

    // stage self edges
    if (t < ROWS) {
        *(f16x8*)&estage[t * 8] = *(const f16x8*)&t16s[(size_t)(r0 + t) * 8];
        edst[t] = (unsigned short)t;
    }
    // stage real edges: 1 scattered 16B request per edge
    for (int i = t; i < ecount; i += 256) {
        int c = col[e0 + i];
        *(f16x8*)&estage[(ROWS + i) * 8] = *(const f16x8*)&t16s[(size_t)c * 8];
        int ge = e0 + i;                       // dst-local via 4-step binary search
        int lo = 0, hi = ROWS;
        while (hi - lo > 1) {
            int mid = (lo + hi) >> 1;
            if (ge >= rowb[mid]) lo = mid; else hi = mid;
        }
        edst[ROWS + i] = (unsigned short)lo;
    }
    __syncthreads();

    int wave = t >> 6, lane = t & 63;
    int m = lane & 15, quad = lane >> 4;

    // B-frags for this wave's 2 col tiles (cols wave*32 .. +31); quads 1-3 are the
    // K=8..31 zero-pad rows of Wc.
    f16x8 bfr0 = {}, bfr1 = {};
    if (quad == 0) {
        bfr0 = *(const f16x8*)&WcbL[(wave * 32 + m) * 8];
        bfr1 = *(const f16x8*)&WcbL[(wave * 32 + 16 + m) * 8];
    }
    float bb0 = b1v[wave * 32 + m];
    float bb1 = b1v[wave * 32 + 16 + m];

    int ntile = (etot + 15) / 16;
    for (int tt = 0; tt < ntile; tt++) {
        int ebase = tt * 16;
        f16x8 a = {};
        if (quad == 0 && ebase + m < etot)
            a = *(const f16x8*)&estage[(ebase + m) * 8];
        f32x4 z0 = {}, z1 = {};
        z0 = __builtin_amdgcn_mfma_f32_16x16x32_f16(a, bfr0, z0, 0, 0, 0);
        z1 = __builtin_amdgcn_mfma_f32_16x16x32_f16(a, bfr1, z1, 0, 0, 0);
        // my 4 output edges: ebase + quad*4 + r
        float di4[4];
        int dl4[4];
#pragma unroll
        for (int r = 0; r < 4; r++) {
            int oe = ebase + quad * 4 + r;
            bool vld = oe < etot;
            di4[r] = vld ? (float)estage[oe * 8 + 7] : 0.f;  // di_src (0 -> contributes 0)
            dl4[r] = vld ? (int)edst[oe] : 0;
        }
#pragma unroll
        for (int r = 0; r < 4; r++) {
            float v0 = fmaxf(z0[r] + bb0, 0.f) * di4[r];
            float v1 = fmaxf(z1[r] + bb1, 0.f) * di4[r];
            atomicAdd(&accum[dl4[r] * ASTR + wave * 32 + m], v0);
            atomicAdd(&accum[dl4[r] * ASTR + wave * 32 + 16 + m], v1);
        }
    }
    __syncthreads();

    // W2 MFMA phase on the fp32 aggregate (convert to fp16 frags), round-0 layout
    int col_base = wave * 32;
    f32x4 acc2[2] = {};
#pragma unroll
    for (int k0 = 0; k0 < 128; k0 += 32) {
        const float* ap = &accum[m * ASTR + k0 + quad * 8];
        f16x8 a2;
#pragma unroll
        for (int j = 0; j < 8; j++) a2[j] = (_Float16)ap[j];
#pragma unroll
        for (int ct = 0; ct < 2; ct++) {
            f16x8 bw = *(const f16x8*)(Wt2 + (size_t)(col_base + ct * 16 + m) * 128
                                       + k0 + quad * 8);
            acc2[ct] = __builtin_amdgcn_mfma_f32_16x16x32_f16(a2, bw, acc2[ct], 0, 0, 0);
        }
    }
    __syncthreads();

    // epilogue: h2 -> Hs, pool by sorted batch (proven round-0 form)
#pragma unroll
    for (int r = 0; r < 4; r++) {
        int rll = quad * 4 + r;
        int rw = r0 + rll;
        float di = (rw < n) ? dinv[rw] : 0.f;
#pragma unroll
        for (int ct = 0; ct < 2; ct++) {
            int colb = col_base + ct * 16 + m;
            float v = fmaxf(di * acc2[ct][r] + b2v[colb], 0.f);
            Hs[rll * 128 + colb] = (rw < n) ? v : 0.f;
        }
    }
    __syncthreads();
    if (t < 128) {
        int colb = t;
        float s = 0.f, mx = 0.f;
        int gcur = batch[r0 < n ? r0 : (n - 1)];
        for (int rr = 0; rr < ROWS; rr++) {
            int rw = r0 + rr;
            if (rw >= n) break;
            int gi = batch[rw];
            if (gi != gcur) {
                atomicAdd(&psum[gcur * 128 + colb], s);
                atomicMax((int*)&pmax[gcur * 128 + colb], __float_as_int(mx));
                s = 0.f; mx = 0.f; gcur = gi;
            }
            float v = Hs[rr * 128 + colb];
            s += v;
            mx = fmaxf(mx, v);
        }
        atomicAdd(&psum[gcur * 128 + colb], s);
        atomicMax((int*)&pmax[gcur * 128 + colb], __float_as_int(mx));
    }
}

// ---------------- final ----------------

__global__ void k_final(const float* __restrict__ psum, const float* __restrict__ pmax,
                        const float* __restrict__ pcnt, const float* __restrict__ Wp,
                        const float* __restrict__ bp, float* __restrict__ out) {
    int t = blockIdx.x * blockDim.x + threadIdx.x;
    if (t >= N_GRAPHS * 256) return;
    int g = t >> 8, j = t & 255;
    float inv = 1.0f / fmaxf(pcnt[g], 1.0f);
    float acc = bp[j];
#pragma unroll 4
    for (int k = 0; k < 128; k++) acc += (psum[g * 128 + k] * inv) * Wp[k * 256 + j];
#pragma unroll 4
    for (int k = 0; k < 128; k++) acc += pmax[g * 128 + k] * Wp[(128 + k) * 256 + j];
    out[t] = fmaxf(acc, 0.f);
}

extern "C" void kernel_launch(void* const* d_in, const int* in_sizes, int n_in,
                              void* d_out, int out_size, void* d_ws, size_t ws_size,
                              hipStream_t stream) {
    const int N = N_NODES, E = N_EDGES;
    const float* x    = (const float*)d_in[0];
    const int*   ei   = (const int*)d_in[1];
    const int*   src  = ei;
    const int*   dst  = ei + E;
    const int*   batch= (const int*)d_in[2];
    const float* W_in = (const float*)d_in[3];
    const float* b_in = (const float*)d_in[4];
    const float* W1   = (const float*)d_in[5];
    const float* b1   = (const float*)d_in[6];
    const float* W2   = (const float*)d_in[7];
    const float* b2   = (const float*)d_in[8];
    const float* Wp   = (const float*)d_in[9];
    const float* bp   = (const float*)d_in[10];
    float* out = (float*)d_out;

    char* p8 = (char*)d_ws;
    int* totals      = (int*)p8;   p8 += 256 * 4;
    int* bucket_base = (int*)p8;   p8 += 256 * 4;
    int* gcursor     = (int*)p8;   p8 += 256 * 4;
    int* row_ptr     = (int*)p8;   p8 += (N_PAD + 64) * 4;
    int* col         = (int*)p8;   p8 += (size_t)N_EDGES * 4;
    unsigned* esort  = (unsigned*)p8; p8 += (size_t)N_EDGES * 4;
    float* dinv      = (float*)p8; p8 += N_PAD * 4;
    _Float16* Wcb    = (_Float16*)p8; p8 += 1024 * 2;         // ([W_in;b_in]@W1)^T fp16
    _Float16* Wt2    = (_Float16*)p8; p8 += 128 * 128 * 2;
    float* pfeat     = (float*)p8; p8 += (size_t)N_PAD * 8 * 4; // dinv*[x,1] fp32
    _Float16* t16s   = (_Float16*)p8; p8 += (size_t)N_PAD * 8 * 2; // di*[t,1] fp16 16B/node
    float* psum      = (float*)p8; p8 += N_GRAPHS * 128 * 4;
    float* pmax      = (float*)p8; p8 += N_GRAPHS * 128 * 4;
    float* pcnt      = (float*)p8;

    const int TB = 256;
    dim3 blk(TB);

    // prep: Wt2 transpose + Wcb + pool/cursor zero
    k_prep<<<(128 * 128 + 1024 + TB - 1) / TB, blk, 0, stream>>>(
        W_in, b_in, W1, W2, Wt2, Wcb, psum, pmax, totals);

    // CSR build
    k_coarse_hist<<<CB, blk, 0, stream>>>(dst, totals);
    k_bucket_scan<<<1, blk, 0, stream>>>(totals, bucket_base, gcursor, batch, pcnt);
    k_coarse_scatter<<<CB, blk, 0, stream>>>(src, dst, gcursor, esort);
    k_fine_fill_p<<<NBUCKET, blk, 0, stream>>>(esort, bucket_base, col, row_ptr, dinv,
                                               x, pfeat);

    // layer 1 state: t16s = fp16(di*[A@p, 1])  (1 request/edge, L2-resident pfeat)
    k_agg_t<<<(N + 31) / 32, blk, 0, stream>>>(pfeat, row_ptr, col, dinv, t16s, N);

    // layer 2: per-edge g1 recompute (1x16B request/edge) + agg + W2 MFMA + pooling
    k_gnn2r<<<N / 16, blk, 0, stream>>>(
        t16s, row_ptr, col, Wcb, b1, Wt2, b2, dinv, batch, psum, pmax, N);

    // final MLP
    k_final<<<(N_GRAPHS * 256 + TB - 1) / TB, blk, 0, stream>>>(psum, pmax, pcnt, Wp, bp, out);
}

// Round 8
// 193.000 us; speedup vs baseline: 4.0245x; 4.0245x over previous
//
#include <hip/hip_runtime.h>
#include <hip/hip_fp16.h>

#define N_NODES 50000
#define N_EDGES 800000
#define N_GRAPHS 64
#define N_PAD 50048

#define CB 256                              // coarse-pass blocks
#define EPB (N_EDGES / CB)                  // 3125 edges per block (exact)
#define NBUCKET ((N_NODES + 255) / 256)     // 196 coarse buckets (dst>>8)

typedef _Float16 f16x8 __attribute__((ext_vector_type(8)));
typedef float f32x4 __attribute__((ext_vector_type(4)));

// fp8 e4m3 <-> f16 via bit-splice: byte b at f16 bits [14:7] represents value*2^-8
// (exact for normals and subnormals). The 2^8/32 net scale is folded into Wt2.
__device__ __forceinline__ unsigned splice2(unsigned z) {
    return ((z & 0x80u) << 8) | ((z & 0x7fu) << 7) |
           ((z & 0x8000u) << 16) | ((z & 0x7f00u) << 15);
}
__device__ __forceinline__ f16x8 dec8(uint2 w) {
    union { unsigned u[4]; f16x8 v; } o;
    o.u[0] = splice2(w.x);
    o.u[1] = splice2(w.x >> 16);
    o.u[2] = splice2(w.y);
    o.u[3] = splice2(w.y >> 16);
    return o.v;
}

// ---------------- prep: Wt2*8 ->fp16, Wcz = [W_in;b_in]@W1 fp32, pcnt, zeros --------

__global__ void k_prep(const float* __restrict__ W_in, const float* __restrict__ b_in,
                       const float* __restrict__ W1, const float* __restrict__ W2,
                       _Float16* __restrict__ Wt2, float* __restrict__ Wcz,
                       float* psum, float* pmax, int* totals, int* gcursor,
                       const int* __restrict__ batch, float* __restrict__ pcnt) {
    int idx = blockIdx.x * blockDim.x + threadIdx.x;
    if (idx < 128 * 128) {                   // Wt2[n*128+k] = 8 * W2[k*128+n]
        int n = idx >> 7, k = idx & 127;     // (x8 compensates fp8 stored value = G/8)
        Wt2[idx] = (_Float16)(W2[k * 128 + n] * 8.0f);
    } else if (idx < 128 * 128 + 1024) {     // Wcz[k*128+ch], k<6: W_in@W1, k=6: b_in@W1
        int j = idx - 128 * 128;
        int ch = j >> 3, k = j & 7;
        float acc = 0.f;
        if (k < 6) {
            for (int q = 0; q < 64; q++) acc += W_in[k * 64 + q] * W1[q * 128 + ch];
        } else if (k == 6) {
            for (int q = 0; q < 64; q++) acc += b_in[q] * W1[q * 128 + ch];
        }
        Wcz[k * 128 + ch] = acc;
    }
    if (idx < N_GRAPHS * 128) { psum[idx] = 0.f; pmax[idx] = 0.f; }
    if (idx < 256) { totals[idx] = 0; gcursor[idx] = 0; }
    // pcnt via lower_bound on sorted batch (block 0 only)
    if (blockIdx.x == 0) {
        __shared__ int shp[N_GRAPHS + 1];
        int tt = threadIdx.x;
        if (tt <= N_GRAPHS) {
            int lo = 0, hi = N_NODES;
            while (lo < hi) {
                int mid = (lo + hi) >> 1;
                if (batch[mid] < tt) lo = mid + 1; else hi = mid;
            }
            shp[tt] = lo;
        }
        __syncthreads();
        if (tt < N_GRAPHS) pcnt[tt] = (float)(shp[tt + 1] - shp[tt]);
    }
}

// ---------------- CSR build ----------------

__global__ __launch_bounds__(256) void k_coarse_hist(const int* __restrict__ dst,
                                                     int* __restrict__ totals) {
    __shared__ int hist[NBUCKET];
    int t = threadIdx.x, b = blockIdx.x;
    for (int i = t; i < NBUCKET; i += 256) hist[i] = 0;
    __syncthreads();
    int e0 = b * EPB;
    for (int e = e0 + t; e < e0 + EPB; e += 256)
        atomicAdd(&hist[dst[e] >> 8], 1);
    __syncthreads();
    for (int i = t; i < NBUCKET; i += 256)
        if (hist[i] > 0) atomicAdd(&totals[i], hist[i]);
}

// scan(totals) done redundantly per block (replaces the 1-block k_bucket_scan);
// gcursor is a zero-based per-bucket running offset; slot = local scan base + offset.
__global__ __launch_bounds__(256) void k_scan_scatter(
        const int* __restrict__ src, const int* __restrict__ dst,
        const int* __restrict__ totals, int* __restrict__ bucket_base,
        int* __restrict__ gcursor, unsigned int* __restrict__ esort) {
    __shared__ int cur[256];
    __shared__ int sc[256];
    int t = threadIdx.x, b = blockIdx.x;
    cur[t] = 0;
    __syncthreads();
    int e0 = b * EPB;
    for (int e = e0 + t; e < e0 + EPB; e += 256)
        atomicAdd(&cur[dst[e] >> 8], 1);
    __syncthreads();
    int lcnt = cur[t];
    int v = (t < NBUCKET) ? totals[t] : 0;
    sc[t] = v;
    __syncthreads();
    for (int off = 1; off < 256; off <<= 1) {
        int u = (t >= off) ? sc[t - off] : 0;
        __syncthreads();
        sc[t] += u;
        __syncthreads();
    }
    int base = sc[t] - v;
    int off = (t < NBUCKET && lcnt > 0) ? atomicAdd(&gcursor[t], lcnt) : 0;
    cur[t] = base + off;
    if (b == 0) {
        if (t < NBUCKET) bucket_base[t] = base;
        if (t == 0) bucket_base[NBUCKET] = N_EDGES;
    }
    __syncthreads();
    for (int e = e0 + t; e < e0 + EPB; e += 256) {
        int d = dst[e];
        int slot = atomicAdd(&cur[d >> 8], 1);
        esort[slot] = ((unsigned)(d & 255) << 16) | (unsigned)src[e];  // src < 2^16
    }
}

// fine hist -> row_ptr/dinv, cursor fill of col; store p[node] = dinv*[x0..x5, 1, 0]
__global__ __launch_bounds__(256) void k_fine_fill_p(
        const unsigned int* __restrict__ esort, const int* __restrict__ bucket_base,
        int* __restrict__ col, int* __restrict__ row_ptr, float* __restrict__ dinv,
        const float* __restrict__ x, float* __restrict__ p) {
    __shared__ int hist[256];
    __shared__ int sc[256];
    __shared__ int cur[256];
    int t = threadIdx.x, b = blockIdx.x;
    hist[t] = 0;
    __syncthreads();
    int base = bucket_base[b], end = bucket_base[b + 1];
    for (int e = base + t; e < end; e += 256)
        atomicAdd(&hist[(esort[e] >> 16) & 255], 1);
    __syncthreads();
    int v = hist[t];
    sc[t] = v;
    __syncthreads();
    for (int off = 1; off < 256; off <<= 1) {
        int u = (t >= off) ? sc[t - off] : 0;
        __syncthreads();
        sc[t] += u;
        __syncthreads();
    }
    int start = base + sc[t] - v;
    cur[t] = start;
    int node = b * 256 + t;
    float di = rsqrtf((float)(v + 1));  // +1 self-loop
    if (node < N_NODES) {
        row_ptr[node] = start;
        dinv[node] = di;
        float pr[8];
#pragma unroll
        for (int k = 0; k < 6; k++) pr[k] = x[node * 6 + k] * di;
        pr[6] = di;      // multiplies the fused bias row (b_in@W1)
        pr[7] = 0.f;
        *(f32x4*)&p[(size_t)node * 8] = *(f32x4*)&pr[0];
        *(f32x4*)&p[(size_t)node * 8 + 4] = *(f32x4*)&pr[4];
    }
    if (b == 0 && t == 0) row_ptr[N_NODES] = N_EDGES;
    __syncthreads();
    for (int e = base + t; e < end; e += 256) {
        unsigned pk = esort[e];
        int slot = atomicAdd(&cur[(pk >> 16) & 255], 1);
        col[slot] = (int)(pk & 0xffffu);
    }
}

// ---------------- layer 1: L2-resident 8-ch gather + fused 7x128 projection ---------
// t = A@[x*dinv, dinv]; z1 = dinv*(t@Wc) + b1; G = relu(z1)*dinv, stored as fp8 e4m3
// of value 32*G (bit-splice from f16(G/8)), 128 B/node -> layer-2 gather = 1 line/edge.
__global__ __launch_bounds__(256, 8) void k_agg_proj(
        const float* __restrict__ p, const int* __restrict__ row_ptr,
        const int* __restrict__ col, const float* __restrict__ Wcz,
        const float* __restrict__ b1, const float* __restrict__ dinv,
        unsigned char* __restrict__ g1, int n) {
    __shared__ float tl[32][8];
    __shared__ float Wl[8 * 128];
    __shared__ float bl[128];
    int t = threadIdx.x;
    for (int i = t; i < 1024; i += 256) Wl[i] = Wcz[i];
    if (t < 128) bl[t] = b1[t];

    // gather phase: 8 threads/row, 1 fp32 channel each, 4 loads in flight
    int rg = t >> 3, ck = t & 7;
    int row = blockIdx.x * 32 + rg;
    float acc = 0.f;
    if (row < n) {
        acc = p[(size_t)row * 8 + ck];  // self term
        int e = row_ptr[row], e1 = row_ptr[row + 1];
        for (; e + 3 < e1; e += 4) {
            int c0 = col[e], c1 = col[e + 1], c2 = col[e + 2], c3 = col[e + 3];
            float v0 = p[(size_t)c0 * 8 + ck];
            float v1 = p[(size_t)c1 * 8 + ck];
            float v2 = p[(size_t)c2 * 8 + ck];
            float v3 = p[(size_t)c3 * 8 + ck];
            acc += (v0 + v1) + (v2 + v3);
        }
        for (; e < e1; e++) acc += p[(size_t)col[e] * 8 + ck];
    }
    tl[rg][ck] = acc;
    __syncthreads();

    // projection phase: thread -> (row, 16-ch slice); fp8 pack + 16B store
    int rg2 = t >> 3, oc = t & 7;
    int row2 = blockIdx.x * 32 + rg2;
    if (row2 < n) {
        float tr[7];
#pragma unroll
        for (int k = 0; k < 7; k++) tr[k] = tl[rg2][k];
        float di = dinv[row2];
        unsigned w[4] = {0u, 0u, 0u, 0u};
#pragma unroll
        for (int c = 0; c < 16; c++) {
            int ch = oc * 16 + c;
            float z = 0.f;
#pragma unroll
            for (int k = 0; k < 7; k++) z += tr[k] * Wl[k * 128 + ch];
            z = di * z + bl[ch];
            float h = fmaxf(z, 0.f) * di;           // G
            union { _Float16 f; unsigned short u; } cv;
            cv.f = (_Float16)(h * 0.125f);          // G/8 = (32G)*2^-8
            unsigned hb = cv.u;
            unsigned r = hb & 0x7fffu;
            r = r + 0x3fu + ((r >> 7) & 1u);        // RTN-even at bit 7
            unsigned byte = ((hb >> 8) & 0x80u) | ((r >> 7) & 0x7fu);
            w[c >> 2] |= byte << ((c & 3) * 8);
        }
        *(uint4*)&g1[(size_t)row2 * 128 + oc * 16] = make_uint4(w[0], w[1], w[2], w[3]);
    }
}

// ---------------- layer 2: fp8 gather (1 line/edge) + MFMA + fused pooling ----------
__global__ __launch_bounds__(256, 8) void k_gnn2f8(
        const unsigned char* __restrict__ g, const int* __restrict__ row_ptr,
        const int* __restrict__ col, const _Float16* __restrict__ Wt2,
        const float* __restrict__ b2, const float* __restrict__ dinv,
        const int* __restrict__ batch, float* __restrict__ psum,
        float* __restrict__ pmax, int n) {
    constexpr int ROWS = 16, KP = 136;
    __shared__ __align__(16) char smem[ROWS * 128 * 4];   // Hs 8KB > Sl 4.25KB
    _Float16* Sl = (_Float16*)smem;
    float* Hs = (float*)smem;          // aliases Sl; used only after Sl is dead
    int t = threadIdx.x;

    // gather phase: 16 threads/row x 8 fp8 ch; row = 128 B = ONE line-request/edge
    {
        int rl = t >> 4, ck = t & 15;
        int row = blockIdx.x * ROWS + rl;
        f16x8 accA = {};
        f16x8 accB = {};
        const uint2* gb = (const uint2*)g;
        if (row < n) {
            accA = dec8(gb[(size_t)row * 16 + ck]);   // self term
            int e = row_ptr[row], e1 = row_ptr[row + 1];
            for (; e + 3 < e1; e += 4) {
                int c0 = col[e], c1 = col[e + 1], c2 = col[e + 2], c3 = col[e + 3];
                uint2 v0 = gb[(size_t)c0 * 16 + ck];
                uint2 v1 = gb[(size_t)c1 * 16 + ck];
                uint2 v2 = gb[(size_t)c2 * 16 + ck];
                uint2 v3 = gb[(size_t)c3 * 16 + ck];
                accA += dec8(v0);
                accB += dec8(v1);
                accA += dec8(v2);
                accB += dec8(v3);
            }
            if (e + 1 < e1) {
                uint2 v0 = gb[(size_t)col[e] * 16 + ck];
                uint2 v1 = gb[(size_t)col[e + 1] * 16 + ck];
                accA += dec8(v0);
                accB += dec8(v1);
                e += 2;
            }
            if (e < e1) accA += dec8(gb[(size_t)col[e] * 16 + ck]);
        }
        f16x8 o = accA + accB;
        *(f16x8*)&Sl[rl * KP + ck * 8] = o;
    }
    __syncthreads();

    // MFMA phase (K=128): wave -> cols wave*32..+32 (2 tiles)
    int wave = t >> 6;
    int lane = t & 63;
    int m = lane & 15;
    int quad = lane >> 4;
    int col_base = wave * 32;

    f32x4 acc[2] = {};
#pragma unroll
    for (int k0 = 0; k0 < 128; k0 += 32) {
        f16x8 a = *(const f16x8*)&Sl[m * KP + k0 + quad * 8];
#pragma unroll
        for (int ct = 0; ct < 2; ct++) {
            f16x8 bw = *(const f16x8*)(Wt2 + (size_t)(col_base + ct * 16 + m) * 128
                                       + k0 + quad * 8);
            acc[ct] = __builtin_amdgcn_mfma_f32_16x16x32_f16(a, bw, acc[ct], 0, 0, 0);
        }
    }

    // epilogue: h2 -> Hs, pool by sorted batch
    __syncthreads();  // all Sl reads complete before overwriting smem
#pragma unroll
    for (int r = 0; r < 4; r++) {
        int rl = quad * 4 + r;
        int row = blockIdx.x * ROWS + rl;
        float di = (row < n) ? dinv[row] : 0.f;
#pragma unroll
        for (int ct = 0; ct < 2; ct++) {
            int colb = col_base + ct * 16 + m;
            float v = fmaxf(di * acc[ct][r] + b2[colb], 0.f);
            Hs[rl * 128 + colb] = (row < n) ? v : 0.f;
        }
    }
    __syncthreads();
    if (t < 128) {
        int colb = t;
        int row0b = blockIdx.x * ROWS;
        float s = 0.f, mx = 0.f;
        int gcur = batch[row0b < n ? row0b : (n - 1)];
        for (int rr = 0; rr < ROWS; rr++) {
            int row = row0b + rr;
            if (row >= n) break;
            int gi = batch[row];
            if (gi != gcur) {
                atomicAdd(&psum[gcur * 128 + colb], s);
                atomicMax((int*)&pmax[gcur * 128 + colb], __float_as_int(mx));
                s = 0.f; mx = 0.f; gcur = gi;
            }
            float v = Hs[rr * 128 + colb];
            s += v;
            mx = fmaxf(mx, v);
        }
        atomicAdd(&psum[gcur * 128 + colb], s);
        atomicMax((int*)&pmax[gcur * 128 + colb], __float_as_int(mx));
    }
}

// ---------------- final ----------------

__global__ void k_final(const float* __restrict__ psum, const float* __restrict__ pmax,
                        const float* __restrict__ pcnt, const float* __restrict__ Wp,
                        const float* __restrict__ bp, float* __restrict__ out) {
    int t = blockIdx.x * blockDim.x + threadIdx.x;
    if (t >= N_GRAPHS * 256) return;
    int g = t >> 8, j = t & 255;
    float inv = 1.0f / fmaxf(pcnt[g], 1.0f);
    float acc = bp[j];
#pragma unroll 4
    for (int k = 0; k < 128; k++) acc += (psum[g * 128 + k] * inv) * Wp[k * 256 + j];
#pragma unroll 4
    for (int k = 0; k < 128; k++) acc += pmax[g * 128 + k] * Wp[(128 + k) * 256 + j];
    out[t] = fmaxf(acc, 0.f);
}

extern "C" void kernel_launch(void* const* d_in, const int* in_sizes, int n_in,
                              void* d_out, int out_size, void* d_ws, size_t ws_size,
                              hipStream_t stream) {
    const int N = N_NODES, E = N_EDGES;
    const float* x    = (const float*)d_in[0];
    const int*   ei   = (const int*)d_in[1];
    const int*   src  = ei;
    const int*   dst  = ei + E;
    const int*   batch= (const int*)d_in[2];
    const float* W_in = (const float*)d_in[3];
    const float* b_in = (const float*)d_in[4];
    const float* W1   = (const float*)d_in[5];
    const float* b1   = (const float*)d_in[6];
    const float* W2   = (const float*)d_in[7];
    const float* b2   = (const float*)d_in[8];
    const float* Wp   = (const float*)d_in[9];
    const float* bp   = (const float*)d_in[10];
    float* out = (float*)d_out;

    char* p8 = (char*)d_ws;
    int* totals      = (int*)p8;   p8 += 256 * 4;
    int* bucket_base = (int*)p8;   p8 += 256 * 4;
    int* gcursor     = (int*)p8;   p8 += 256 * 4;
    int* row_ptr     = (int*)p8;   p8 += (N_PAD + 64) * 4;
    int* col         = (int*)p8;   p8 += (size_t)N_EDGES * 4;
    unsigned* esort  = (unsigned*)p8; p8 += (size_t)N_EDGES * 4;
    float* dinv      = (float*)p8; p8 += N_PAD * 4;
    float* Wcz       = (float*)p8; p8 += 1024 * 4;            // fused [W_in;b_in]@W1
    _Float16* Wt2    = (_Float16*)p8; p8 += 128 * 128 * 2;    // 8*W2^T fp16
    float* pfeat     = (float*)p8; p8 += (size_t)N_PAD * 8 * 4; // dinv*[x,1] fp32
    unsigned char* g1f8 = (unsigned char*)p8; p8 += (size_t)N_PAD * 128; // fp8 g1
    float* psum      = (float*)p8; p8 += N_GRAPHS * 128 * 4;
    float* pmax      = (float*)p8; p8 += N_GRAPHS * 128 * 4;
    float* pcnt      = (float*)p8;

    const int TB = 256;
    dim3 blk(TB);

    // prep: Wt2(x8) + Wcz + pcnt + zeros
    k_prep<<<(128 * 128 + 1024 + TB - 1) / TB, blk, 0, stream>>>(
        W_in, b_in, W1, W2, Wt2, Wcz, psum, pmax, totals, gcursor, batch, pcnt);

    // CSR build (scan merged into scatter)
    k_coarse_hist<<<CB, blk, 0, stream>>>(dst, totals);
    k_scan_scatter<<<CB, blk, 0, stream>>>(src, dst, totals, bucket_base, gcursor, esort);
    k_fine_fill_p<<<NBUCKET, blk, 0, stream>>>(esort, bucket_base, col, row_ptr, dinv,
                                               x, pfeat);

    // layer 1: 8-ch fp32 gather (L2-resident) + fused projection -> g1 fp8 (128 B/row)
    k_agg_proj<<<(N + 31) / 32, blk, 0, stream>>>(pfeat, row_ptr, col, Wcz, b1, dinv,
                                                  g1f8, N);

    // layer 2: fp8 gather (1 line/edge) + MFMA + fused pooling
    k_gnn2f8<<<(N + 15) / 16, blk, 0, stream>>>(
        g1f8, row_ptr, col, Wt2, b2, dinv, batch, psum, pmax, N);

    // final MLP
    k_final<<<(N_GRAPHS * 256 + TB - 1) / TB, blk, 0, stream>>>(psum, pmax, pcnt, Wp, bp, out);
}